// Round 2
// baseline (621.202 us; speedup 1.0000x reference)
//
#include <hip/hip_runtime.h>
#include <stdint.h>

typedef unsigned short u16;
typedef __attribute__((ext_vector_type(8))) short bf16x8;   // 8 bf16 (4 VGPRs) — MFMA A/B frag
typedef __attribute__((ext_vector_type(4))) float f32x4;    // MFMA C/D frag

static __device__ __forceinline__ u16 f2bf(float f) {
  uint32_t u = __float_as_uint(f);
  return (u16)((u + 0x7fffu + ((u >> 16) & 1u)) >> 16);   // RNE
}
static __device__ __forceinline__ float bf2f(u16 h) {
  return __uint_as_float(((uint32_t)h) << 16);
}

static __device__ __forceinline__ void gload_lds16(const void* g, void* l) {
  __builtin_amdgcn_global_load_lds((const __attribute__((address_space(1))) void*)g,
                                   (__attribute__((address_space(3))) void*)l, 16, 0, 0);
}

// ---------------- elementwise f32 -> bf16 cast ----------------
__global__ __launch_bounds__(256) void cast_bf16_kernel(const float* __restrict__ in,
                                                        u16* __restrict__ out, int n4) {
  int idx = blockIdx.x * 256 + threadIdx.x;
  if (idx >= n4) return;
  float4 v = ((const float4*)in)[idx];
  u16 o0 = f2bf(v.x), o1 = f2bf(v.y), o2 = f2bf(v.z), o3 = f2bf(v.w);
  uint2 packed;
  packed.x = (uint32_t)o0 | ((uint32_t)o1 << 16);
  packed.y = (uint32_t)o2 | ((uint32_t)o3 << 16);
  ((uint2*)out)[idx] = packed;
}

// ---------------- transpose + cast: f32 [4096][4096] -> bf16 transposed ----------------
__global__ __launch_bounds__(256) void transpose_cast_kernel(const float* __restrict__ in,
                                                             u16* __restrict__ out) {
  __shared__ float t[64][72];
  const int r0 = blockIdx.y * 64, c0 = blockIdx.x * 64;
  const int tid = threadIdx.x;
  const int rr = tid >> 4;          // 0..15
  const int c4 = (tid & 15) * 4;
#pragma unroll
  for (int s = 0; s < 4; ++s) {
    float4 v = *(const float4*)&in[(size_t)(r0 + rr + s * 16) * 4096 + c0 + c4];
    *(float4*)&t[rr + s * 16][c4] = v;   // 72*4=288 B rows -> 16B-aligned
  }
  __syncthreads();
  const int oc = tid >> 2;          // 0..63  (output row within tile = input col)
  const int or16 = (tid & 3) * 16;
  bf16x8 o0, o1;
#pragma unroll
  for (int u = 0; u < 8; ++u) o0[u] = (short)f2bf(t[or16 + u][oc]);
#pragma unroll
  for (int u = 0; u < 8; ++u) o1[u] = (short)f2bf(t[or16 + 8 + u][oc]);
  *(bf16x8*)&out[(size_t)(c0 + oc) * 4096 + r0 + or16] = o0;
  *(bf16x8*)&out[(size_t)(c0 + oc) * 4096 + r0 + or16 + 8] = o1;
}

// ---------------- transpose: bf16 [4096][4096] -> bf16 transposed ----------------
__global__ __launch_bounds__(256) void transpose_bf16_kernel(const u16* __restrict__ in,
                                                             u16* __restrict__ out) {
  __shared__ u16 t[64][72];
  const int r0 = blockIdx.y * 64, c0 = blockIdx.x * 64;
  const int tid = threadIdx.x;
  const int rr = tid >> 3;          // 0..31
  const int c8 = (tid & 7) * 8;
#pragma unroll
  for (int s = 0; s < 2; ++s) {
    bf16x8 v = *(const bf16x8*)&in[(size_t)(r0 + rr + s * 32) * 4096 + c0 + c8];
    *(bf16x8*)&t[rr + s * 32][c8] = v;   // 72*2=144 B rows -> 16B-aligned
  }
  __syncthreads();
  const int oc = tid >> 2;
  const int or16 = (tid & 3) * 16;
  bf16x8 o0, o1;
#pragma unroll
  for (int u = 0; u < 8; ++u) o0[u] = (short)t[or16 + u][oc];
#pragma unroll
  for (int u = 0; u < 8; ++u) o1[u] = (short)t[or16 + 8 + u][oc];
  *(bf16x8*)&out[(size_t)(c0 + oc) * 4096 + r0 + or16] = o0;
  *(bf16x8*)&out[(size_t)(c0 + oc) * 4096 + r0 + or16 + 8] = o1;
}

// ---------------- kern[i][t] = sum_j H[i][j] * W2[t][j] ----------------
__global__ __launch_bounds__(256) void kern_reduce_kernel(const u16* __restrict__ H,
                                                          const float* __restrict__ W2,
                                                          float* __restrict__ kern) {
  const int i = blockIdx.x;
  const int tid = threadIdx.x;
  float acc[9];
#pragma unroll
  for (int t = 0; t < 9; ++t) acc[t] = 0.f;
#pragma unroll
  for (int it = 0; it < 2; ++it) {
    const int j = (it * 256 + tid) * 8;
    bf16x8 hv = *(const bf16x8*)&H[(size_t)i * 4096 + j];
    float hf[8];
#pragma unroll
    for (int u = 0; u < 8; ++u) hf[u] = bf2f((u16)hv[u]);
#pragma unroll
    for (int t = 0; t < 9; ++t) {
      float s = 0.f;
#pragma unroll
      for (int u = 0; u < 8; ++u) s += hf[u] * W2[t * 4096 + j + u];
      acc[t] += s;
    }
  }
  __shared__ float red[4 * 9];
  const int lane = tid & 63, wid = tid >> 6;
#pragma unroll
  for (int t = 0; t < 9; ++t) {
    float v = acc[t];
#pragma unroll
    for (int off = 32; off > 0; off >>= 1) v += __shfl_down(v, off);
    if (lane == 0) red[wid * 9 + t] = v;
  }
  __syncthreads();
  if (tid < 9) kern[(size_t)i * 9 + tid] = red[tid] + red[9 + tid] + red[18 + tid] + red[27 + tid];
}

// ---------------- depthwise 3x3 conv + leaky -> bf16 ----------------
__global__ __launch_bounds__(256) void dwconv_kernel(const float* __restrict__ x,
                                                     const float* __restrict__ kern,
                                                     u16* __restrict__ V) {
  const int ch = blockIdx.x;
  __shared__ float img[4096];
  const float* src = x + (size_t)ch * 4096;
#pragma unroll
  for (int s = 0; s < 4; ++s)
    ((float4*)img)[s * 256 + threadIdx.x] = ((const float4*)src)[s * 256 + threadIdx.x];
  float kv[9];
#pragma unroll
  for (int t = 0; t < 9; ++t) kv[t] = kern[(size_t)ch * 9 + t];
  __syncthreads();
#pragma unroll
  for (int s = 0; s < 16; ++s) {
    const int p = s * 256 + threadIdx.x;
    const int h = p >> 6, w = p & 63;
    float sum = 0.f;
#pragma unroll
    for (int dh = -1; dh <= 1; ++dh) {
      const int hh = h + dh;
      if ((unsigned)hh < 64u) {
#pragma unroll
        for (int dw = -1; dw <= 1; ++dw) {
          const int wwi = w + dw;
          if ((unsigned)wwi < 64u) sum += img[hh * 64 + wwi] * kv[(dh + 1) * 3 + (dw + 1)];
        }
      }
    }
    sum = sum >= 0.f ? sum : 0.1f * sum;
    V[(size_t)ch * 4096 + p] = f2bf(sum);
  }
}

// ---------------- NT GEMM: C[m][n] = sum_k A[m][k]*B[n][k], bf16 in, fp32 acc ----------------
// EPI: 0 = leaky -> bf16 out ; 1 = sigmoid -> bf16 out ; 2 = +bias +deg*att -> f32 out
template <int EPI>
__global__ __launch_bounds__(256, 2) void gemm_nt(const u16* __restrict__ A,
                                                  const u16* __restrict__ B,
                                                  void* __restrict__ Cout,
                                                  int M, int N, int K,
                                                  const float* __restrict__ bias,
                                                  const float* __restrict__ degf,
                                                  const u16* __restrict__ att) {
  __shared__ u16 Asm[128 * 64];
  __shared__ u16 Bsm[128 * 64];
  const int tid = threadIdx.x;
  const int lane = tid & 63;
  const int wid = tid >> 6;
  const int wr = wid >> 1, wc = wid & 1;       // 2x2 wave grid, 64x64 per wave
  const int bm = blockIdx.y * 128;
  const int bn = blockIdx.x * 128;
  const int srow = tid >> 3;                    // 0..31 staging row
  const int sseg = (tid & 7) * 8;               // 16B segment within 64-elem row
  const int l15 = lane & 15;
  const int lk = (lane >> 4) * 8;

  f32x4 acc[4][4];
#pragma unroll
  for (int m = 0; m < 4; ++m)
#pragma unroll
    for (int n = 0; n < 4; ++n) acc[m][n] = (f32x4){0.f, 0.f, 0.f, 0.f};

  const size_t aBase = (size_t)bm * K;
  const size_t bBase = (size_t)bn * K;

  for (int kt = 0; kt < K; kt += 64) {
    __syncthreads();
#pragma unroll
    for (int bi = 0; bi < 4; ++bi) {
      const u16* ga = A + aBase + (size_t)(bi * 32 + srow) * K + kt + sseg;
      gload_lds16(ga, &Asm[(bi * 32 + srow) * 64 + sseg]);
      const u16* gb = B + bBase + (size_t)(bi * 32 + srow) * K + kt + sseg;
      gload_lds16(gb, &Bsm[(bi * 32 + srow) * 64 + sseg]);
    }
    __syncthreads();
#pragma unroll
    for (int ks = 0; ks < 2; ++ks) {
      bf16x8 av[4], bv[4];
#pragma unroll
      for (int m = 0; m < 4; ++m)
        av[m] = *(const bf16x8*)&Asm[(wr * 64 + m * 16 + l15) * 64 + ks * 32 + lk];
#pragma unroll
      for (int n = 0; n < 4; ++n)
        bv[n] = *(const bf16x8*)&Bsm[(wc * 64 + n * 16 + l15) * 64 + ks * 32 + lk];
#pragma unroll
      for (int m = 0; m < 4; ++m)
#pragma unroll
        for (int n = 0; n < 4; ++n)
          acc[m][n] = __builtin_amdgcn_mfma_f32_16x16x32_bf16(av[m], bv[n], acc[m][n], 0, 0, 0);
    }
  }

  // epilogue: C/D layout col=lane&15, row=(lane>>4)*4+reg  [m89-verified]
#pragma unroll
  for (int m = 0; m < 4; ++m) {
    const int row0 = bm + wr * 64 + m * 16 + (lane >> 4) * 4;
#pragma unroll
    for (int n = 0; n < 4; ++n) {
      const int col = bn + wc * 64 + n * 16 + l15;
#pragma unroll
      for (int j = 0; j < 4; ++j) {
        const int row = row0 + j;
        float v = acc[m][n][j];
        const size_t idx = (size_t)row * N + col;
        if (EPI == 0) {
          v = v >= 0.f ? v : 0.1f * v;
          ((u16*)Cout)[idx] = f2bf(v);
        } else if (EPI == 1) {
          v = 1.f / (1.f + __expf(-v));
          ((u16*)Cout)[idx] = f2bf(v);
        } else {
          v += bias[row] + degf[idx] * bf2f(att[idx]);
          ((float*)Cout)[idx] = v;
        }
      }
    }
  }
}

extern "C" void kernel_launch(void* const* d_in, const int* in_sizes, int n_in,
                              void* d_out, int out_size, void* d_ws, size_t ws_size,
                              hipStream_t stream) {
  const float* xc  = (const float*)d_in[0];   // (1,4096,64,64)
  const float* deg = (const float*)d_in[1];   // (4096,4096)
  const float* W1  = (const float*)d_in[2];   // (4096,4096)
  const float* W2  = (const float*)d_in[3];   // (9,4096)
  const float* Wc  = (const float*)d_in[4];   // (4096,4096)
  const float* bc  = (const float*)d_in[5];   // (4096,)
  const float* Wd1 = (const float*)d_in[6];   // (512,4096)
  const float* Wd2 = (const float*)d_in[7];   // (4096,512)
  float* out = (float*)d_out;

  char* ws = (char*)d_ws;
  const size_t MB = 1ull << 20;
  u16* RA    = (u16*)(ws + 0 * MB);     // 32MB: degT -> deg_b -> V
  u16* RB    = (u16*)(ws + 32 * MB);    // 32MB: W1_b -> Vt
  u16* RC    = (u16*)(ws + 64 * MB);    // 32MB: H -> Wc_b
  u16* ATT   = (u16*)(ws + 96 * MB);    // 32MB: att (bf16)
  u16* WD1B  = (u16*)(ws + 128 * MB);   // 4MB
  u16* WD2B  = (u16*)(ws + 132 * MB);   // 4MB
  u16* HIDT  = (u16*)(ws + 136 * MB);   // 4MB
  float* KERN = (float*)(ws + 140 * MB); // 144KB

  // ---- CA branch ----
  cast_bf16_kernel<<<2048, 256, 0, stream>>>(Wd1, WD1B, 512 * 4096 / 4);
  cast_bf16_kernel<<<2048, 256, 0, stream>>>(Wd2, WD2B, 4096 * 512 / 4);
  transpose_cast_kernel<<<dim3(64, 64), 256, 0, stream>>>(deg, RA);   // degT[p][c]
  // hidT[p][o] = leaky(sum_c degT[p][c] * Wd1[o][c]) : M=4096 N=512 K=4096
  gemm_nt<0><<<dim3(4, 32), 256, 0, stream>>>(RA, WD1B, HIDT, 4096, 512, 4096,
                                              nullptr, nullptr, nullptr);
  // att[o][p] = sigmoid(sum_k Wd2[o][k] * hidT[p][k]) : M=4096 N=4096 K=512
  gemm_nt<1><<<dim3(32, 32), 256, 0, stream>>>(WD2B, HIDT, ATT, 4096, 4096, 512,
                                               nullptr, nullptr, nullptr);

  // ---- dynamic kernel generation ----
  cast_bf16_kernel<<<16384, 256, 0, stream>>>(deg, RA, 4096 * 4096 / 4);  // deg_b
  cast_bf16_kernel<<<16384, 256, 0, stream>>>(W1, RB, 4096 * 4096 / 4);   // W1_b
  // H[i][j] = leaky(sum_k deg[i][k] * W1[j][k]) : 4096^3
  gemm_nt<0><<<dim3(32, 32), 256, 0, stream>>>(RA, RB, RC, 4096, 4096, 4096,
                                               nullptr, nullptr, nullptr);
  kern_reduce_kernel<<<4096, 256, 0, stream>>>(RC, W2, KERN);

  // ---- depthwise conv + transpose ----
  dwconv_kernel<<<4096, 256, 0, stream>>>(xc, KERN, RA);                  // V[c][p]
  transpose_bf16_kernel<<<dim3(64, 64), 256, 0, stream>>>(RA, RB);        // Vt[p][c]

  // ---- 1x1 conv + fused epilogue ----
  cast_bf16_kernel<<<16384, 256, 0, stream>>>(Wc, RC, 4096 * 4096 / 4);   // Wc_b
  // out[o][p] = sum_c Wc[o][c]*V[c][p] + bc[o] + deg[o][p]*att[o][p] : 4096^3
  gemm_nt<2><<<dim3(32, 32), 256, 0, stream>>>(RC, RB, out, 4096, 4096, 4096,
                                               bc, deg, ATT);
}